// Round 1
// baseline (284.092 us; speedup 1.0000x reference)
//
#include <hip/hip_runtime.h>

#define BATCH 8
#define CIN   64
#define COUT  64
#define HH    128
#define WW    128
#define ALPHA 8.3f
#define TPX   64          // pixels per block along x
#define CC    8           // channel chunk staged in LDS
#define XW    (TPX + 8)   // padded LDS row width (need 66)
#define OWP   (COUT + 4)  // padded weight row (bank-conflict relief)

__global__ __launch_bounds__(256)
void depthconv_kernel(const float* __restrict__ image,
                      const float* __restrict__ depth,
                      const float* __restrict__ weight,
                      const float* __restrict__ bias,
                      float* __restrict__ out) {
    __shared__ float s_img[CC][3][XW];   //  6912 B
    __shared__ float s_w[CC][9][OWP];    // 19584 B
    __shared__ float s_sim[9][TPX];      //  2304 B
    __shared__ float s_d[3][XW];         //   864 B

    const int tid  = threadIdx.x;
    const int tile = blockIdx.x;          // 2048 tiles = 8 b * 128 y * 2 xt
    const int xt   = tile & 1;
    const int y    = (tile >> 1) & (HH - 1);
    const int b    = tile >> 8;
    const int x0   = xt * TPX;

    // ---- stage depth rows (y-1..y+1, x0-1..x0+64), zero-padded ----
    for (int idx = tid; idx < 3 * XW; idx += 256) {
        int r = idx / XW, xx = idx % XW;
        int gy = y + r - 1, gx = x0 - 1 + xx;
        float v = 0.f;
        if (xx < TPX + 2 && (unsigned)gy < HH && (unsigned)gx < WW)
            v = depth[(b * HH + gy) * WW + gx];
        s_d[r][xx] = v;
    }
    __syncthreads();

    // ---- sim[k][p] = exp(-alpha*|d_tap - d_tap0|);  tap0 = (y-1, x-1) ----
    for (int idx = tid; idx < 9 * TPX; idx += 256) {
        int p = idx & (TPX - 1);
        int k = idx >> 6;                 // 0..8
        int i = k / 3, j = k % 3;
        float dt = s_d[i][p + j];
        float dc = s_d[0][p];             // centre_idx == 0 -> tap (-1,-1)
        s_sim[k][p] = __expf(-ALPHA * fabsf(dt - dc));
    }
    __syncthreads();

    const int og = tid >> 4;              // 0..15 -> o_base = og*4
    const int pg = tid & 15;              // 0..15 -> p_base = pg*4
    const int o_base = og * 4;
    const int p_base = pg * 4;

    float sreg[9][4];
    #pragma unroll
    for (int k = 0; k < 9; ++k)
        #pragma unroll
        for (int pi = 0; pi < 4; ++pi)
            sreg[k][pi] = s_sim[k][p_base + pi];

    float acc[4][4];
    #pragma unroll
    for (int oi = 0; oi < 4; ++oi)
        #pragma unroll
        for (int pi = 0; pi < 4; ++pi)
            acc[oi][pi] = 0.f;

    for (int cc = 0; cc < CIN / CC; ++cc) {
        __syncthreads();   // protect previous chunk's LDS from overwrite

        // stage image chunk: CC channels x 3 rows x 66 px (zero-padded)
        for (int idx = tid; idx < CC * 3 * XW; idx += 256) {
            int c   = idx / (3 * XW);
            int rem = idx % (3 * XW);
            int r = rem / XW, xx = rem % XW;
            int gy = y + r - 1, gx = x0 - 1 + xx;
            float v = 0.f;
            if (xx < TPX + 2 && (unsigned)gy < HH && (unsigned)gx < WW)
                v = image[((b * CIN + cc * CC + c) * HH + gy) * WW + gx];
            s_img[c][r][xx] = v;
        }
        // stage weight chunk: global o-major (coalesced) -> LDS [c][k][o]
        for (int idx = tid; idx < CC * 9 * COUT; idx += 256) {
            int o   = idx / (CC * 9);
            int rem = idx % (CC * 9);
            int c = rem / 9, k = rem % 9;
            s_w[c][k][o] = weight[(o * CIN + cc * CC + c) * 9 + k];
        }
        __syncthreads();

        for (int c = 0; c < CC; ++c) {
            float a[3][6];
            #pragma unroll
            for (int r = 0; r < 3; ++r) {
                float4 v0 = *(const float4*)&s_img[c][r][p_base];
                float2 v1 = *(const float2*)&s_img[c][r][p_base + 4];
                a[r][0] = v0.x; a[r][1] = v0.y; a[r][2] = v0.z; a[r][3] = v0.w;
                a[r][4] = v1.x; a[r][5] = v1.y;
            }
            #pragma unroll
            for (int k = 0; k < 9; ++k) {
                const int i = k / 3, j = k % 3;
                float4 wv = *(const float4*)&s_w[c][k][o_base];
                float m0 = a[i][j + 0] * sreg[k][0];
                float m1 = a[i][j + 1] * sreg[k][1];
                float m2 = a[i][j + 2] * sreg[k][2];
                float m3 = a[i][j + 3] * sreg[k][3];
                acc[0][0] = fmaf(wv.x, m0, acc[0][0]);
                acc[0][1] = fmaf(wv.x, m1, acc[0][1]);
                acc[0][2] = fmaf(wv.x, m2, acc[0][2]);
                acc[0][3] = fmaf(wv.x, m3, acc[0][3]);
                acc[1][0] = fmaf(wv.y, m0, acc[1][0]);
                acc[1][1] = fmaf(wv.y, m1, acc[1][1]);
                acc[1][2] = fmaf(wv.y, m2, acc[1][2]);
                acc[1][3] = fmaf(wv.y, m3, acc[1][3]);
                acc[2][0] = fmaf(wv.z, m0, acc[2][0]);
                acc[2][1] = fmaf(wv.z, m1, acc[2][1]);
                acc[2][2] = fmaf(wv.z, m2, acc[2][2]);
                acc[2][3] = fmaf(wv.z, m3, acc[2][3]);
                acc[3][0] = fmaf(wv.w, m0, acc[3][0]);
                acc[3][1] = fmaf(wv.w, m1, acc[3][1]);
                acc[3][2] = fmaf(wv.w, m2, acc[3][2]);
                acc[3][3] = fmaf(wv.w, m3, acc[3][3]);
            }
        }
    }

    // ---- epilogue: add bias, vectorized store ----
    float4 bv = *(const float4*)&bias[o_base];
    float barr[4] = {bv.x, bv.y, bv.z, bv.w};
    #pragma unroll
    for (int oi = 0; oi < 4; ++oi) {
        float4 res;
        res.x = acc[oi][0] + barr[oi];
        res.y = acc[oi][1] + barr[oi];
        res.z = acc[oi][2] + barr[oi];
        res.w = acc[oi][3] + barr[oi];
        *(float4*)&out[((b * COUT + o_base + oi) * HH + y) * WW + x0 + p_base] = res;
    }
}

extern "C" void kernel_launch(void* const* d_in, const int* in_sizes, int n_in,
                              void* d_out, int out_size, void* d_ws, size_t ws_size,
                              hipStream_t stream) {
    const float* image  = (const float*)d_in[0];
    const float* depth  = (const float*)d_in[1];
    const float* weight = (const float*)d_in[2];
    const float* bias   = (const float*)d_in[3];
    float* out = (float*)d_out;

    dim3 grid(BATCH * HH * (WW / TPX));   // 2048
    dim3 block(256);
    depthconv_kernel<<<grid, block, 0, stream>>>(image, depth, weight, bias, out);
}

// Round 3
// 134.337 us; speedup vs baseline: 2.1148x; 2.1148x over previous
//
#include <hip/hip_runtime.h>
#include <hip/hip_bf16.h>

#define BATCH 8
#define CIN   64
#define COUT  64
#define HH    128
#define WW    128
#define ALPHA 8.3f
#define TPX   64
#define YPB   4
#define XW    66

typedef __attribute__((ext_vector_type(8))) short short8;   // 8 bf16 = 4 VGPR
typedef __attribute__((ext_vector_type(4))) float f32x4;

// index (in shorts) into s_img[3][XW][64], XOR-swizzled in 8-short (16B) slots
__device__ __forceinline__ int img_idx(int r, int x, int c) {
    return (((r * XW + x) << 6) + c) ^ ((x & 7) << 3);
}

// pre-kernel: weight [o][c][k] f32 -> wt [k][o][c] bf16
__global__ __launch_bounds__(256)
void transpose_w(const float* __restrict__ w, __hip_bfloat16* __restrict__ wt) {
    int i = blockIdx.x * 256 + threadIdx.x;           // dest-order index
    if (i >= 9 * 64 * 64) return;
    int c = i & 63;
    int o = (i >> 6) & 63;
    int tap = i >> 12;
    wt[i] = __float2bfloat16(w[(o * 64 + c) * 9 + tap]);
}

__global__ __launch_bounds__(256)
void depthconv_mfma(const float* __restrict__ image,
                    const float* __restrict__ depth,
                    const float* __restrict__ bias,
                    const short* __restrict__ wt,     // [9][64 o][64 c] bf16
                    float* __restrict__ out) {
    __shared__ short s_img[3 * XW * 64];              // 25344 B
    __shared__ float s_d[3][XW];
    __shared__ float s_sim[9][TPX];

    const int tid = threadIdx.x;
    const int bid = blockIdx.x;
    const int yg = bid & 31;                          // 32 y-groups of YPB rows
    const int xt = (bid >> 5) & 1;
    const int b  = bid >> 6;
    const int x0 = xt * TPX;

    const int lane = tid & 63;
    const int wid  = tid >> 6;                        // 4 waves
    const int l15  = lane & 15;
    const int lq   = lane >> 4;                       // 0..3
    const int o_base = wid * 16;

    // ---- per-block weight A-fragments: lane: row o=o_base+l15, k c=h*32+lq*8+j ----
    short8 wfrag[9][2];
    #pragma unroll
    for (int tap = 0; tap < 9; ++tap)
        #pragma unroll
        for (int h = 0; h < 2; ++h)
            wfrag[tap][h] = *(const short8*)&wt[(tap * 64 + o_base + l15) * 64 + h * 32 + lq * 8];

    float bias_v[4];
    #pragma unroll
    for (int r = 0; r < 4; ++r) bias_v[r] = bias[o_base + lq * 4 + r];

    for (int yi = 0; yi < YPB; ++yi) {
        const int y = yg * YPB + yi;
        __syncthreads();                              // protect prev iteration's LDS

        // ---- stage image tile: bf16, transposed [r][x][c], swizzled ----
        for (int i = tid; i < 3 * XW * 32; i += 256) {
            int x  = i % XW;
            int rr = (i / XW) % 3;
            int c  = (i / (3 * XW)) * 2;              // channel pair
            int gy = y + rr - 1, gx = x0 - 1 + x;
            float v0 = 0.f, v1 = 0.f;
            if ((unsigned)gy < HH && (unsigned)gx < WW) {
                const float* p = &image[((b * CIN + c) * HH + gy) * WW + gx];
                v0 = p[0];
                v1 = p[HH * WW];
            }
            __hip_bfloat162 pk = __float22bfloat162_rn(float2{v0, v1});
            *(__hip_bfloat162*)&s_img[img_idx(rr, x, c)] = pk;
        }
        // ---- stage depth rows ----
        for (int i = tid; i < 3 * XW; i += 256) {
            int x = i % XW, rr = i / XW;
            int gy = y + rr - 1, gx = x0 - 1 + x;
            float v = 0.f;
            if ((unsigned)gy < HH && (unsigned)gx < WW)
                v = depth[(b * HH + gy) * WW + gx];
            s_d[rr][x] = v;
        }
        __syncthreads();

        // ---- sim[tap][p] = exp(-a*|d_tap - d_tap0|), tap0 = (-1,-1) ----
        for (int i = tid; i < 9 * TPX; i += 256) {
            int p = i & 63, tap = i >> 6;
            int ri = tap / 3, dj = tap % 3;
            float dt = s_d[ri][p + dj];
            float dc = s_d[0][p];
            s_sim[tap][p] = __expf(-ALPHA * fabsf(dt - dc));
        }
        __syncthreads();

        // ---- per-tap GEMM + sim-weighted accumulate ----
        f32x4 acc[4];
        #pragma unroll
        for (int nt = 0; nt < 4; ++nt) acc[nt] = f32x4{0.f, 0.f, 0.f, 0.f};

        #pragma unroll
        for (int tap = 0; tap < 9; ++tap) {
            const int ri = tap / 3, dj = tap % 3;
            float sv[4];
            #pragma unroll
            for (int nt = 0; nt < 4; ++nt) sv[nt] = s_sim[tap][nt * 16 + l15];
            #pragma unroll
            for (int nt = 0; nt < 4; ++nt) {
                const int xi = nt * 16 + l15 + dj;    // staged-x of this pixel+tap
                short8 b0 = *(const short8*)&s_img[img_idx(ri, xi, lq * 8)];
                f32x4 tmp = __builtin_amdgcn_mfma_f32_16x16x32_bf16(
                    wfrag[tap][0], b0, (f32x4){0.f, 0.f, 0.f, 0.f}, 0, 0, 0);
                short8 b1 = *(const short8*)&s_img[img_idx(ri, xi, 32 + lq * 8)];
                tmp = __builtin_amdgcn_mfma_f32_16x16x32_bf16(
                    wfrag[tap][1], b1, tmp, 0, 0, 0);
                #pragma unroll
                for (int r = 0; r < 4; ++r)
                    acc[nt][r] = fmaf(sv[nt], tmp[r], acc[nt][r]);
            }
        }

        // ---- store: col=pixel, row=cout -> 4x64B segments per instr ----
        #pragma unroll
        for (int nt = 0; nt < 4; ++nt) {
            int px = x0 + nt * 16 + l15;
            #pragma unroll
            for (int r = 0; r < 4; ++r) {
                int o = o_base + lq * 4 + r;
                out[((b * COUT + o) * HH + y) * WW + px] = acc[nt][r] + bias_v[r];
            }
        }
    }
}

extern "C" void kernel_launch(void* const* d_in, const int* in_sizes, int n_in,
                              void* d_out, int out_size, void* d_ws, size_t ws_size,
                              hipStream_t stream) {
    const float* image  = (const float*)d_in[0];
    const float* depth  = (const float*)d_in[1];
    const float* weight = (const float*)d_in[2];
    const float* bias   = (const float*)d_in[3];
    float* out = (float*)d_out;
    __hip_bfloat16* wt = (__hip_bfloat16*)d_ws;       // 9*64*64 bf16 = 73728 B

    transpose_w<<<(9 * 64 * 64 + 255) / 256, 256, 0, stream>>>(weight, wt);

    dim3 grid(BATCH * 2 * (HH / YPB));                // 8 * 2 * 32 = 512
    depthconv_mfma<<<grid, 256, 0, stream>>>(image, depth, bias,
                                             (const short*)wt, out);
}